// Round 5
// baseline (293.654 us; speedup 1.0000x reference)
//
#include <hip/hip_runtime.h>
#include <hip/hip_bf16.h>
#include <math.h>

#define NB 8192
#define DD 512
#define HH 256
#define BM 128
#define BN 256
#define BK 32
#define KT (DD / BK)       // 16
#define NCT (NB / BN)      // 32 column groups
#define NCAND 8
#define MR 16              // mlp rows per block

typedef __attribute__((ext_vector_type(8))) short bf16x8;
typedef __attribute__((ext_vector_type(4))) float f32x4;

#define AS1(p) ((const __attribute__((address_space(1))) void*)(p))
#define AS3(p) ((__attribute__((address_space(3))) void*)(p))

// ---------------- Kernel 1: fused MLP (bit-exact fp32 chains, 16 rows/block) ----------------
__global__ __launch_bounds__(256)
void mlp_kernel(const float* __restrict__ sess, const float* __restrict__ W1,
                const float* __restrict__ b1, const float* __restrict__ W2,
                const float* __restrict__ b2, float* __restrict__ proj,
                __hip_bfloat16* __restrict__ projb) {
    __shared__ float srow[MR][DD];  // 32 KB
    __shared__ float sh[MR][HH];    // 16 KB
    const int t = threadIdx.x;      // 256
    const int r0 = blockIdx.x * MR;

    const float4* src = (const float4*)(sess + (size_t)r0 * DD);
    float4* dst = (float4*)&srow[0][0];
#pragma unroll
    for (int i = 0; i < (MR * DD / 4) / 256; ++i) dst[t + i * 256] = src[t + i * 256];
    __syncthreads();

    float acc[MR];
#pragma unroll
    for (int r = 0; r < MR; ++r) acc[r] = b1[t];
    for (int k4 = 0; k4 < DD / 4; ++k4) {
        const int k = k4 * 4;
        float w0 = W1[(k + 0) * HH + t];
        float w1 = W1[(k + 1) * HH + t];
        float w2 = W1[(k + 2) * HH + t];
        float w3 = W1[(k + 3) * HH + t];
#pragma unroll
        for (int r = 0; r < MR; ++r) {
            float4 s4 = *(const float4*)&srow[r][k];
            acc[r] = fmaf(s4.x, w0, acc[r]);
            acc[r] = fmaf(s4.y, w1, acc[r]);
            acc[r] = fmaf(s4.z, w2, acc[r]);
            acc[r] = fmaf(s4.w, w3, acc[r]);
        }
    }
#pragma unroll
    for (int r = 0; r < MR; ++r) sh[r][t] = fmaxf(acc[r], 0.f);
    __syncthreads();

    float a0[MR], a1[MR];
#pragma unroll
    for (int r = 0; r < MR; ++r) { a0[r] = b2[t]; a1[r] = b2[t + 256]; }
    for (int k4 = 0; k4 < HH / 4; ++k4) {
        const int k = k4 * 4;
        float w0 = W2[(k + 0) * DD + t], u0 = W2[(k + 0) * DD + t + 256];
        float w1 = W2[(k + 1) * DD + t], u1 = W2[(k + 1) * DD + t + 256];
        float w2 = W2[(k + 2) * DD + t], u2 = W2[(k + 2) * DD + t + 256];
        float w3 = W2[(k + 3) * DD + t], u3 = W2[(k + 3) * DD + t + 256];
#pragma unroll
        for (int r = 0; r < MR; ++r) {
            float4 h4 = *(const float4*)&sh[r][k];
            a0[r] = fmaf(h4.x, w0, a0[r]); a1[r] = fmaf(h4.x, u0, a1[r]);
            a0[r] = fmaf(h4.y, w1, a0[r]); a1[r] = fmaf(h4.y, u1, a1[r]);
            a0[r] = fmaf(h4.z, w2, a0[r]); a1[r] = fmaf(h4.z, u2, a1[r]);
            a0[r] = fmaf(h4.w, w3, a0[r]); a1[r] = fmaf(h4.w, u3, a1[r]);
        }
    }
#pragma unroll
    for (int r = 0; r < MR; ++r) {
        size_t i0 = (size_t)(r0 + r) * DD + t;
        size_t i1 = i0 + 256;
        proj[i0] = a0[r];
        proj[i1] = a1[r];
        projb[i0] = __float2bfloat16(a0[r]);
        projb[i1] = __float2bfloat16(a1[r]);
    }
}

// merge two sorted-desc triples -> top-3 (value-only compare)
__device__ __forceinline__ void merge3(float& a0, float& a1, float& a2, int& x0, int& x1, int& x2,
                                       float b0, float b1, float b2, int y0, int y1, int y2) {
    bool c0 = a0 > b0;
    float r0 = c0 ? a0 : b0; int s0 = c0 ? x0 : y0;
    bool c1 = c0 ? (a1 > b0) : (a0 > b1);
    float r1 = c0 ? (c1 ? a1 : b0) : (c1 ? a0 : b1);
    int   s1 = c0 ? (c1 ? x1 : y0) : (c1 ? x0 : y1);
    int na = (int)c0 + (int)c1;
    float ca = (na == 2) ? a2 : ((na == 1) ? a1 : a0);
    int   cx = (na == 2) ? x2 : ((na == 1) ? x1 : x0);
    float cb = (na == 2) ? b0 : ((na == 1) ? b1 : b2);
    int   cy = (na == 2) ? y0 : ((na == 1) ? y1 : y2);
    bool c2 = ca > cb;
    a0 = r0; x0 = s0; a1 = r1; x1 = s1;
    a2 = c2 ? ca : cb; x2 = c2 ? cx : cy;
}

__device__ __forceinline__ void ins3(float v, int jg, float& v0, float& v1, float& v2,
                                     int& j0, int& j1, int& j2) {
    bool g2 = v > v2, g1 = v > v1, g0 = v > v0;
    float v2a = g2 ? v : v2; int j2a = g2 ? jg : j2;
    v2 = g1 ? v1 : v2a;      j2 = g1 ? j1 : j2a;
    float v1a = g1 ? v : v1; int j1a = g1 ? jg : j1;
    v1 = g0 ? v0 : v1a;      j1 = g0 ? j0 : j1a;
    v0 = g0 ? v : v0;        j0 = g0 ? jg : j0;
}

// ------------- Kernel 2: bf16 MFMA sim (128x256), overlap-scheduled dbuf, fused top-3 -------------
__global__ __launch_bounds__(256)
void sim_mfma_kernel(const short* __restrict__ projb,
                     float* __restrict__ pvals, int* __restrict__ pidx) {
    __shared__ short smem[2 * BM * BK + 2 * BN * BK];   // 48 KB
    short* As = smem;                 // [2][BM*BK]
    short* Bs = smem + 2 * BM * BK;   // [2][BN*BK]
    unsigned long long* ev = (unsigned long long*)smem; // epilogue overlay [128][25]

    const int t = threadIdx.x;
    const int w = t >> 6, l = t & 63;
    const int wr = w >> 1, wc = w & 1;
    const int tx = l & 15, tg = l >> 4;
    const int rb = blockIdx.x * BM;
    const int jb = blockIdx.y * BN;

    const int rin = l >> 2;                         // row within 16-row chunk
    const int tgs = (l & 3) ^ ((rin >> 1) & 3);     // pre-swizzled 16B-slot in 64B row
    const int loff = tx * BK + ((tg ^ ((tx >> 1) & 3)) << 3);  // swizzled read offset

    f32x4 acc[4][8];
#pragma unroll
    for (int i = 0; i < 4; ++i)
#pragma unroll
        for (int j = 0; j < 8; ++j) acc[i][j] = (f32x4){0.f, 0.f, 0.f, 0.f};

#define STAGE(buf, k0)                                                                      \
    {                                                                                       \
        _Pragma("unroll")                                                                   \
        for (int q = 0; q < 6; ++q) {                                                       \
            int c = w * 6 + q;                                                              \
            if (c < 8) {                                                                    \
                const short* g = projb + (size_t)(rb + c * 16 + rin) * DD + (k0) + tgs * 8; \
                __builtin_amdgcn_global_load_lds(AS1(g), AS3(As + (buf) * (BM * BK) + c * 512), 16, 0, 0); \
            } else {                                                                        \
                int cb = c - 8;                                                             \
                const short* g = projb + (size_t)(jb + cb * 16 + rin) * DD + (k0) + tgs * 8; \
                __builtin_amdgcn_global_load_lds(AS1(g), AS3(Bs + (buf) * (BN * BK) + cb * 512), 16, 0, 0); \
            }                                                                               \
        }                                                                                   \
    }

    // COMPUTE: ds_reads + MFMA with NO fence between them — the compiler's
    // fine-grained lgkmcnt interleave keeps the MFMA pipe fed while reads land.
#define COMPUTE(kt)                                                                          \
    {                                                                                        \
        const short* Ab = As + ((kt) & 1) * (BM * BK);                                       \
        const short* Bb = Bs + ((kt) & 1) * (BN * BK);                                       \
        bf16x8 af[4], bfr[8];                                                                \
        _Pragma("unroll")                                                                    \
        for (int mi = 0; mi < 4; ++mi)                                                       \
            af[mi] = *(const bf16x8*)&Ab[(wr * 64 + mi * 16) * BK + loff];                   \
        _Pragma("unroll")                                                                    \
        for (int nj = 0; nj < 8; ++nj)                                                       \
            bfr[nj] = *(const bf16x8*)&Bb[(wc * 128 + nj * 16) * BK + loff];                 \
        _Pragma("unroll")                                                                    \
        for (int mi = 0; mi < 4; ++mi)                                                       \
            _Pragma("unroll")                                                                \
            for (int nj = 0; nj < 8; ++nj)                                                   \
                acc[mi][nj] = __builtin_amdgcn_mfma_f32_16x16x32_bf16(af[mi], bfr[nj], acc[mi][nj], 0, 0, 0); \
    }

    STAGE(0, 0);
    STAGE(1, BK);
    for (int kt = 0; kt < KT - 1; ++kt) {
        // top: current buffer's 6 loads retired (FIFO: 12 in flight -> wait to 6)
        asm volatile("s_waitcnt vmcnt(6)" ::: "memory");
        __builtin_amdgcn_sched_barrier(0);
        __builtin_amdgcn_s_barrier();          // buf kt&1 fully staged for all waves
        __builtin_amdgcn_sched_barrier(0);
        COMPUTE(kt);
        // bottom: own reads drained via MFMA operand waits; sync all waves' reads
        __builtin_amdgcn_sched_barrier(0);
        __builtin_amdgcn_s_barrier();          // buf kt&1 free to overwrite
        __builtin_amdgcn_sched_barrier(0);
        if (kt < KT - 2) STAGE(kt & 1, (kt + 2) * BK);
    }
    // peeled last iteration
    asm volatile("s_waitcnt vmcnt(0)" ::: "memory");
    __builtin_amdgcn_sched_barrier(0);
    __builtin_amdgcn_s_barrier();
    __builtin_amdgcn_sched_barrier(0);
    COMPUTE(KT - 1);
#undef STAGE
#undef COMPUTE

    __syncthreads();   // all waves done with LDS tiles before ev overlay

    // ---- epilogue: per-lane top3 over 8 cols, 2-step butterfly, LDS dump, per-row scan ----
#pragma unroll
    for (int mi = 0; mi < 4; ++mi) {
#pragma unroll
        for (int r = 0; r < 4; ++r) {
            float v0 = -INFINITY, v1 = -INFINITY, v2 = -INFINITY;
            int j0 = 0, j1 = 0, j2 = 0;
#pragma unroll
            for (int nj = 0; nj < 8; ++nj)
                ins3(acc[mi][nj][r], jb + wc * 128 + nj * 16 + tx, v0, v1, v2, j0, j1, j2);
#pragma unroll
            for (int s = 1; s <= 2; s <<= 1) {
                float b0v = __shfl_xor(v0, s, 64), b1v = __shfl_xor(v1, s, 64), b2v = __shfl_xor(v2, s, 64);
                int y0 = __shfl_xor(j0, s, 64), y1 = __shfl_xor(j1, s, 64), y2 = __shfl_xor(j2, s, 64);
                merge3(v0, v1, v2, j0, j1, j2, b0v, b1v, b2v, y0, y1, y2);
            }
            if ((tx & 3) == 0) {
                int lrow = wr * 64 + mi * 16 + tg * 4 + r;
                int slot = wc * 4 + (tx >> 2);
                unsigned long long* e = &ev[lrow * 25 + slot * 3];
                e[0] = ((unsigned long long)__float_as_uint(v0) << 32) | (unsigned)j0;
                e[1] = ((unsigned long long)__float_as_uint(v1) << 32) | (unsigned)j1;
                e[2] = ((unsigned long long)__float_as_uint(v2) << 32) | (unsigned)j2;
            }
        }
    }
    __syncthreads();
    if (t < BM) {
        float v0 = -INFINITY, v1 = -INFINITY, v2 = -INFINITY;
        int j0 = 0, j1 = 0, j2 = 0;
        const unsigned long long* e = &ev[t * 25];
#pragma unroll
        for (int s = 0; s < 24; ++s) {
            unsigned long long p = e[s];
            ins3(__uint_as_float((unsigned)(p >> 32)), (int)(unsigned)(p & 0xffffffffu),
                 v0, v1, v2, j0, j1, j2);
        }
        size_t base = ((size_t)(rb + t) * NCT + blockIdx.y) * 3;
        pvals[base + 0] = v0; pvals[base + 1] = v1; pvals[base + 2] = v2;
        pidx[base + 0] = j0; pidx[base + 1] = j1; pidx[base + 2] = j2;
    }
}

// --- Kernel 3: fused merge(top-8) + exact fp64 re-rank + softmax + gather + weighted sum ---
__global__ __launch_bounds__(64)
void rerank_out_kernel(const float* __restrict__ proj, const float* __restrict__ pvals,
                       const int* __restrict__ pidx, const float* __restrict__ sess,
                       float* __restrict__ out, float* __restrict__ cos_out) {
    int r = blockIdx.x;
    int t = threadIdx.x;     // 64 lanes = 1 wave
    float bv[NCAND]; int bj[NCAND];
#pragma unroll
    for (int p = 0; p < NCAND; ++p) { bv[p] = -INFINITY; bj[p] = 0x7fffffff; }
    const float* pv = pvals + (size_t)r * NCT * 3;
    const int* pj = pidx + (size_t)r * NCT * 3;
    for (int s = 0; s < NCT * 3; ++s) {
        float v = pv[s]; int j = pj[s];
        if (!(v > bv[NCAND - 1])) continue;
#pragma unroll
        for (int p = NCAND - 1; p > 0; --p) {
            bool hp = v > bv[p];
            bool gp = v > bv[p - 1];
            bv[p] = hp ? (gp ? bv[p - 1] : v) : bv[p];
            bj[p] = hp ? (gp ? bj[p - 1] : j) : bj[p];
        }
        bool h0 = v > bv[0];
        bv[0] = h0 ? v : bv[0];
        bj[0] = h0 ? j : bj[0];
    }

    const float* pr = proj + (size_t)r * DD;
    float myp[8];
#pragma unroll
    for (int k = 0; k < 8; ++k) myp[k] = pr[t * 8 + k];
    double part[NCAND];
#pragma unroll
    for (int i = 0; i < NCAND; ++i) {
        const float* pc = proj + (size_t)bj[i] * DD;
        double s = 0.0;
#pragma unroll
        for (int k = 0; k < 8; ++k) s += (double)myp[k] * (double)pc[t * 8 + k];
        part[i] = s;
    }
#pragma unroll
    for (int i = 0; i < NCAND; ++i) {
#pragma unroll
        for (int s = 1; s < 64; s <<= 1) part[i] += __shfl_xor(part[i], s, 64);
    }
    double bv0 = -1e300, bv1 = -1e300, bv2 = -1e300;
    int bj0 = 0x7fffffff, bj1 = 0x7fffffff, bj2 = 0x7fffffff;
#pragma unroll
    for (int i = 0; i < NCAND; ++i) {
        double v = part[i]; int j = bj[i];
        bool g2 = (v > bv2) || (v == bv2 && j < bj2);
        bool g1 = (v > bv1) || (v == bv1 && j < bj1);
        bool g0 = (v > bv0) || (v == bv0 && j < bj0);
        if (g2) {
            if (g1) {
                if (g0) { bv2 = bv1; bj2 = bj1; bv1 = bv0; bj1 = bj0; bv0 = v; bj0 = j; }
                else    { bv2 = bv1; bj2 = bj1; bv1 = v; bj1 = j; }
            } else      { bv2 = v; bj2 = j; }
        }
    }
    double e1 = exp(bv1 - bv0), e2 = exp(bv2 - bv0);
    double inv = 1.0 / (1.0 + e1 + e2);
    float w0 = (float)inv, w1 = (float)(e1 * inv), w2 = (float)(e2 * inv);
    if (t == 0) {
        cos_out[r * 3 + 0] = w0; cos_out[r * 3 + 1] = w1; cos_out[r * 3 + 2] = w2;
    }
    const float4* s0 = (const float4*)(sess + (size_t)bj0 * DD);
    const float4* s1 = (const float4*)(sess + (size_t)bj1 * DD);
    const float4* s2 = (const float4*)(sess + (size_t)bj2 * DD);
    float4* o = (float4*)(out + (size_t)r * 3 * DD);
    float4* nb = (float4*)(out + (size_t)NB * 3 * DD + (size_t)r * DD);
#pragma unroll
    for (int e = 0; e < 2; ++e) {
        int q = t + e * 64;          // float4 index 0..127
        float4 x0 = s0[q], x1 = s1[q], x2 = s2[q];
        o[q] = x0; o[128 + q] = x1; o[256 + q] = x2;
        float4 v;
        v.x = fmaf(w0, x0.x, fmaf(w1, x1.x, w2 * x2.x));
        v.y = fmaf(w0, x0.y, fmaf(w1, x1.y, w2 * x2.y));
        v.z = fmaf(w0, x0.z, fmaf(w1, x1.z, w2 * x2.z));
        v.w = fmaf(w0, x0.w, fmaf(w1, x1.w, w2 * x2.w));
        nb[q] = v;
    }
}

extern "C" void kernel_launch(void* const* d_in, const int* in_sizes, int n_in,
                              void* d_out, int out_size, void* d_ws, size_t ws_size,
                              hipStream_t stream) {
    const float* sess = (const float*)d_in[0];
    // d_in[1] = pool_emb: unused by the reference
    const float* W1 = (const float*)d_in[2];
    const float* b1 = (const float*)d_in[3];
    const float* W2 = (const float*)d_in[4];
    const float* b2 = (const float*)d_in[5];
    float* out = (float*)d_out;

    float* proj = (float*)d_ws;                                        // NB*DD f32
    __hip_bfloat16* projb = (__hip_bfloat16*)(proj + (size_t)NB * DD); // NB*DD bf16
    float* pvals = (float*)((char*)projb + (size_t)NB * DD * 2);       // NB*NCT*3 f32
    int*   pidx  = (int*)(pvals + (size_t)NB * NCT * 3);               // NB*NCT*3 i32

    float* cos_out = out + (size_t)NB * 3 * DD + (size_t)NB * DD;

    hipLaunchKernelGGL(mlp_kernel, dim3(NB / MR), dim3(256), 0, stream, sess, W1, b1, W2, b2, proj, projb);
    hipLaunchKernelGGL(sim_mfma_kernel, dim3(NB / BM, NCT), dim3(256), 0, stream, (const short*)projb, pvals, pidx);
    hipLaunchKernelGGL(rerank_out_kernel, dim3(NB), dim3(64), 0, stream, proj, pvals, pidx, sess, out, cos_out);
}

// Round 6
// 285.032 us; speedup vs baseline: 1.0303x; 1.0303x over previous
//
#include <hip/hip_runtime.h>
#include <hip/hip_bf16.h>
#include <math.h>

#define NB 8192
#define DD 512
#define HH 256
#define BT 256             // sim tile (256x256)
#define BK 64
#define KT8 (DD / BK)      // 8 K-tiles
#define NCT (NB / BT)      // 32 column groups
#define NCAND 8
#define MR 16              // mlp rows per block

typedef __attribute__((ext_vector_type(8))) short bf16x8;
typedef __attribute__((ext_vector_type(4))) float f32x4;

#define AS1(p) ((const __attribute__((address_space(1))) void*)(p))
#define AS3(p) ((__attribute__((address_space(3))) void*)(p))

// ---------------- Kernel 1: fused MLP (bit-exact fp32 chains, 16 rows/block) ----------------
__global__ __launch_bounds__(256)
void mlp_kernel(const float* __restrict__ sess, const float* __restrict__ W1,
                const float* __restrict__ b1, const float* __restrict__ W2,
                const float* __restrict__ b2, float* __restrict__ proj,
                __hip_bfloat16* __restrict__ projb) {
    __shared__ float srow[MR][DD];  // 32 KB
    __shared__ float sh[MR][HH];    // 16 KB
    const int t = threadIdx.x;      // 256
    const int r0 = blockIdx.x * MR;

    const float4* src = (const float4*)(sess + (size_t)r0 * DD);
    float4* dst = (float4*)&srow[0][0];
#pragma unroll
    for (int i = 0; i < (MR * DD / 4) / 256; ++i) dst[t + i * 256] = src[t + i * 256];
    __syncthreads();

    float acc[MR];
#pragma unroll
    for (int r = 0; r < MR; ++r) acc[r] = b1[t];
    for (int k4 = 0; k4 < DD / 4; ++k4) {
        const int k = k4 * 4;
        float w0 = W1[(k + 0) * HH + t];
        float w1 = W1[(k + 1) * HH + t];
        float w2 = W1[(k + 2) * HH + t];
        float w3 = W1[(k + 3) * HH + t];
#pragma unroll
        for (int r = 0; r < MR; ++r) {
            float4 s4 = *(const float4*)&srow[r][k];
            acc[r] = fmaf(s4.x, w0, acc[r]);
            acc[r] = fmaf(s4.y, w1, acc[r]);
            acc[r] = fmaf(s4.z, w2, acc[r]);
            acc[r] = fmaf(s4.w, w3, acc[r]);
        }
    }
#pragma unroll
    for (int r = 0; r < MR; ++r) sh[r][t] = fmaxf(acc[r], 0.f);
    __syncthreads();

    float a0[MR], a1[MR];
#pragma unroll
    for (int r = 0; r < MR; ++r) { a0[r] = b2[t]; a1[r] = b2[t + 256]; }
    for (int k4 = 0; k4 < HH / 4; ++k4) {
        const int k = k4 * 4;
        float w0 = W2[(k + 0) * DD + t], u0 = W2[(k + 0) * DD + t + 256];
        float w1 = W2[(k + 1) * DD + t], u1 = W2[(k + 1) * DD + t + 256];
        float w2 = W2[(k + 2) * DD + t], u2 = W2[(k + 2) * DD + t + 256];
        float w3 = W2[(k + 3) * DD + t], u3 = W2[(k + 3) * DD + t + 256];
#pragma unroll
        for (int r = 0; r < MR; ++r) {
            float4 h4 = *(const float4*)&sh[r][k];
            a0[r] = fmaf(h4.x, w0, a0[r]); a1[r] = fmaf(h4.x, u0, a1[r]);
            a0[r] = fmaf(h4.y, w1, a0[r]); a1[r] = fmaf(h4.y, u1, a1[r]);
            a0[r] = fmaf(h4.z, w2, a0[r]); a1[r] = fmaf(h4.z, u2, a1[r]);
            a0[r] = fmaf(h4.w, w3, a0[r]); a1[r] = fmaf(h4.w, u3, a1[r]);
        }
    }
#pragma unroll
    for (int r = 0; r < MR; ++r) {
        size_t i0 = (size_t)(r0 + r) * DD + t;
        size_t i1 = i0 + 256;
        proj[i0] = a0[r];
        proj[i1] = a1[r];
        projb[i0] = __float2bfloat16(a0[r]);
        projb[i1] = __float2bfloat16(a1[r]);
    }
}

// merge two sorted-desc triples -> top-3 (value-only compare)
__device__ __forceinline__ void merge3(float& a0, float& a1, float& a2, int& x0, int& x1, int& x2,
                                       float b0, float b1, float b2, int y0, int y1, int y2) {
    bool c0 = a0 > b0;
    float r0 = c0 ? a0 : b0; int s0 = c0 ? x0 : y0;
    bool c1 = c0 ? (a1 > b0) : (a0 > b1);
    float r1 = c0 ? (c1 ? a1 : b0) : (c1 ? a0 : b1);
    int   s1 = c0 ? (c1 ? x1 : y0) : (c1 ? x0 : y1);
    int na = (int)c0 + (int)c1;
    float ca = (na == 2) ? a2 : ((na == 1) ? a1 : a0);
    int   cx = (na == 2) ? x2 : ((na == 1) ? x1 : x0);
    float cb = (na == 2) ? b0 : ((na == 1) ? b1 : b2);
    int   cy = (na == 2) ? y0 : ((na == 1) ? y1 : y2);
    bool c2 = ca > cb;
    a0 = r0; x0 = s0; a1 = r1; x1 = s1;
    a2 = c2 ? ca : cb; x2 = c2 ? cx : cy;
}

__device__ __forceinline__ void ins3(float v, int jg, float& v0, float& v1, float& v2,
                                     int& j0, int& j1, int& j2) {
    bool g2 = v > v2, g1 = v > v1, g0 = v > v0;
    float v2a = g2 ? v : v2; int j2a = g2 ? jg : j2;
    v2 = g1 ? v1 : v2a;      j2 = g1 ? j1 : j2a;
    float v1a = g1 ? v : v1; int j1a = g1 ? jg : j1;
    v1 = g0 ? v0 : v1a;      j1 = g0 ? j0 : j1a;
    v0 = g0 ? v : v0;        j0 = g0 ? jg : j0;
}

// ------ Kernel 2: bf16 MFMA sim 256x256, BK=64, 4-phase/K-tile counted-vmcnt pipeline ------
// 512 thr = 8 waves (2 wr x 4 wc); per-wave C = 128x64 (acc 8x4 of 16x16 frags).
// LDS (dynamic 128KB): 2 bufs x (A[256][64] + B[256][64]) bf16, slot^=(row&7) XOR swizzle.
__global__ __launch_bounds__(512, 2)
void sim_mfma_kernel(const short* __restrict__ projb,
                     float* __restrict__ pvals, int* __restrict__ pidx) {
    extern __shared__ short smem[];   // 65536 shorts = 128 KB
    unsigned long long* ev = (unsigned long long*)smem;  // epilogue overlay [256][13]

    const int t = threadIdx.x;
    const int wid = t >> 6, l = t & 63;
    const int wr = wid >> 2, wc = wid & 3;
    const int tx = l & 15, tg = l >> 4;
    const int rb = blockIdx.x * BT;
    const int jb = blockIdx.y * BT;

    // staging: lane l covers phys slot (l&7) of row (l>>3); fetch global slot sl = (l&7)^(l>>3)
    const int sl8 = (((l & 7) ^ (l >> 3)) << 3);
    // read swizzle: slot' = (kk*4+tg) ^ (row&7), row&7 == tx&7
    const int sw0 = (((0 * 4 + tg) ^ (tx & 7)) << 3);
    const int sw1 = (((1 * 4 + tg) ^ (tx & 7)) << 3);

    f32x4 acc[8][4];
#pragma unroll
    for (int i = 0; i < 8; ++i)
#pragma unroll
        for (int j = 0; j < 4; ++j) acc[i][j] = (f32x4){0.f, 0.f, 0.f, 0.f};

    // stage half-tile h (0=A0,1=B0,2=A1,3=B1) of K-tile ktn into buffer bufX: 2 loads/thread
#define STAGEH(bufX, ktn, h)                                                                   \
    {                                                                                          \
        const int matB_ = (h) & 1, hh_ = (h) >> 1;                                             \
        const int grow_ = (matB_ ? jb : rb) + hh_ * 128 + wid * 16 + (l >> 3);                 \
        const int gcol_ = (ktn) * 64 + sl8;                                                    \
        const short* g0_ = projb + (size_t)grow_ * DD + gcol_;                                 \
        const short* g1_ = projb + (size_t)(grow_ + 8) * DD + gcol_;                           \
        short* d0_ = smem + (bufX) * 32768 + matB_ * 16384 + hh_ * 8192 + wid * 1024 + l * 8;  \
        __builtin_amdgcn_global_load_lds(AS1(g0_), AS3(d0_), 16, 0, 0);                        \
        __builtin_amdgcn_global_load_lds(AS1(g1_), AS3(d0_ + 512), 16, 0, 0);                  \
    }

    // prologue: stage K-tile 0 fully into buf 0 (8 loads/thread)
#pragma unroll
    for (int h = 0; h < 4; ++h) STAGEH(0, 0, h);

#pragma unroll
    for (int kt = 0; kt < KT8; ++kt) {
        const int buf = kt & 1;
        const short* Ab = smem + buf * 32768;
        const short* Bb = Ab + 16384;

        // ---- K-tile boundary: stage half0(kt+1), counted wait, sync ----
        if (kt < KT8 - 1) {
            STAGEH(buf ^ 1, kt + 1, 0);
            asm volatile("s_waitcnt vmcnt(2)" ::: "memory");   // all of K-tile kt landed
        } else {
            asm volatile("s_waitcnt vmcnt(0)" ::: "memory");   // pipeline drain (last tile)
        }
        __builtin_amdgcn_s_barrier();
        __builtin_amdgcn_sched_barrier(0);

        // ---- phase 0: read A(mi 0,1) + all B, 16 MFMA ----
        bf16x8 bfr[4][2];
#pragma unroll
        for (int nj = 0; nj < 4; ++nj) {
            bfr[nj][0] = *(const bf16x8*)&Bb[(wc * 64 + nj * 16 + tx) * 64 + sw0];
            bfr[nj][1] = *(const bf16x8*)&Bb[(wc * 64 + nj * 16 + tx) * 64 + sw1];
        }
        {
            bf16x8 af00 = *(const bf16x8*)&Ab[(wr * 128 + 0 * 16 + tx) * 64 + sw0];
            bf16x8 af01 = *(const bf16x8*)&Ab[(wr * 128 + 0 * 16 + tx) * 64 + sw1];
            bf16x8 af10 = *(const bf16x8*)&Ab[(wr * 128 + 1 * 16 + tx) * 64 + sw0];
            bf16x8 af11 = *(const bf16x8*)&Ab[(wr * 128 + 1 * 16 + tx) * 64 + sw1];
            asm volatile("s_waitcnt lgkmcnt(0)" ::: "memory");
            __builtin_amdgcn_sched_barrier(0);
            __builtin_amdgcn_s_setprio(1);
#pragma unroll
            for (int nj = 0; nj < 4; ++nj)
                acc[0][nj] = __builtin_amdgcn_mfma_f32_16x16x32_bf16(af00, bfr[nj][0], acc[0][nj], 0, 0, 0);
#pragma unroll
            for (int nj = 0; nj < 4; ++nj)
                acc[1][nj] = __builtin_amdgcn_mfma_f32_16x16x32_bf16(af10, bfr[nj][0], acc[1][nj], 0, 0, 0);
#pragma unroll
            for (int nj = 0; nj < 4; ++nj)
                acc[0][nj] = __builtin_amdgcn_mfma_f32_16x16x32_bf16(af01, bfr[nj][1], acc[0][nj], 0, 0, 0);
#pragma unroll
            for (int nj = 0; nj < 4; ++nj)
                acc[1][nj] = __builtin_amdgcn_mfma_f32_16x16x32_bf16(af11, bfr[nj][1], acc[1][nj], 0, 0, 0);
            __builtin_amdgcn_s_setprio(0);
        }
        __builtin_amdgcn_s_barrier();

        // ---- phases 1..3: read A(mi 2p,2p+1), stage half p of kt+1, 16 MFMA ----
#pragma unroll
        for (int p = 1; p < 4; ++p) {
            bf16x8 af00 = *(const bf16x8*)&Ab[(wr * 128 + (2 * p + 0) * 16 + tx) * 64 + sw0];
            bf16x8 af01 = *(const bf16x8*)&Ab[(wr * 128 + (2 * p + 0) * 16 + tx) * 64 + sw1];
            bf16x8 af10 = *(const bf16x8*)&Ab[(wr * 128 + (2 * p + 1) * 16 + tx) * 64 + sw0];
            bf16x8 af11 = *(const bf16x8*)&Ab[(wr * 128 + (2 * p + 1) * 16 + tx) * 64 + sw1];
            if (kt < KT8 - 1) STAGEH(buf ^ 1, kt + 1, p);
            __builtin_amdgcn_s_barrier();
            asm volatile("s_waitcnt lgkmcnt(0)" ::: "memory");
            __builtin_amdgcn_sched_barrier(0);
            __builtin_amdgcn_s_setprio(1);
#pragma unroll
            for (int nj = 0; nj < 4; ++nj)
                acc[2 * p + 0][nj] = __builtin_amdgcn_mfma_f32_16x16x32_bf16(af00, bfr[nj][0], acc[2 * p + 0][nj], 0, 0, 0);
#pragma unroll
            for (int nj = 0; nj < 4; ++nj)
                acc[2 * p + 1][nj] = __builtin_amdgcn_mfma_f32_16x16x32_bf16(af10, bfr[nj][0], acc[2 * p + 1][nj], 0, 0, 0);
#pragma unroll
            for (int nj = 0; nj < 4; ++nj)
                acc[2 * p + 0][nj] = __builtin_amdgcn_mfma_f32_16x16x32_bf16(af01, bfr[nj][1], acc[2 * p + 0][nj], 0, 0, 0);
#pragma unroll
            for (int nj = 0; nj < 4; ++nj)
                acc[2 * p + 1][nj] = __builtin_amdgcn_mfma_f32_16x16x32_bf16(af11, bfr[nj][1], acc[2 * p + 1][nj], 0, 0, 0);
            __builtin_amdgcn_s_setprio(0);
            __builtin_amdgcn_s_barrier();
        }
    }
#undef STAGEH

    __syncthreads();   // K-loop fully done before ev overlay reuses LDS

    // ---- epilogue: per-lane top3 over 4 nj-cols, 4-step butterfly over tx, dump, scan ----
#pragma unroll
    for (int mi = 0; mi < 8; ++mi) {
#pragma unroll
        for (int rr = 0; rr < 4; ++rr) {
            float v0 = -INFINITY, v1 = -INFINITY, v2 = -INFINITY;
            int j0 = 0, j1 = 0, j2 = 0;
#pragma unroll
            for (int nj = 0; nj < 4; ++nj)
                ins3(acc[mi][nj][rr], jb + wc * 64 + nj * 16 + tx, v0, v1, v2, j0, j1, j2);
#pragma unroll
            for (int s = 1; s < 16; s <<= 1) {
                float b0v = __shfl_xor(v0, s, 64), b1v = __shfl_xor(v1, s, 64), b2v = __shfl_xor(v2, s, 64);
                int y0 = __shfl_xor(j0, s, 64), y1 = __shfl_xor(j1, s, 64), y2 = __shfl_xor(j2, s, 64);
                merge3(v0, v1, v2, j0, j1, j2, b0v, b1v, b2v, y0, y1, y2);
            }
            if (tx == 0) {
                int lrow = wr * 128 + mi * 16 + tg * 4 + rr;
                unsigned long long* e = &ev[lrow * 13 + wc * 3];
                e[0] = ((unsigned long long)__float_as_uint(v0) << 32) | (unsigned)j0;
                e[1] = ((unsigned long long)__float_as_uint(v1) << 32) | (unsigned)j1;
                e[2] = ((unsigned long long)__float_as_uint(v2) << 32) | (unsigned)j2;
            }
        }
    }
    __syncthreads();
    if (t < BT) {
        float v0 = -INFINITY, v1 = -INFINITY, v2 = -INFINITY;
        int j0 = 0, j1 = 0, j2 = 0;
        const unsigned long long* e = &ev[t * 13];
#pragma unroll
        for (int s = 0; s < 12; ++s) {
            unsigned long long p = e[s];
            ins3(__uint_as_float((unsigned)(p >> 32)), (int)(unsigned)(p & 0xffffffffu),
                 v0, v1, v2, j0, j1, j2);
        }
        size_t base = ((size_t)(rb + t) * NCT + blockIdx.y) * 3;
        pvals[base + 0] = v0; pvals[base + 1] = v1; pvals[base + 2] = v2;
        pidx[base + 0] = j0; pidx[base + 1] = j1; pidx[base + 2] = j2;
    }
}

// --- Kernel 3: fused merge(top-8) + exact fp64 re-rank + softmax + gather + weighted sum ---
__global__ __launch_bounds__(64)
void rerank_out_kernel(const float* __restrict__ proj, const float* __restrict__ pvals,
                       const int* __restrict__ pidx, const float* __restrict__ sess,
                       float* __restrict__ out, float* __restrict__ cos_out) {
    int r = blockIdx.x;
    int t = threadIdx.x;     // 64 lanes = 1 wave
    float bv[NCAND]; int bj[NCAND];
#pragma unroll
    for (int p = 0; p < NCAND; ++p) { bv[p] = -INFINITY; bj[p] = 0x7fffffff; }
    const float* pv = pvals + (size_t)r * NCT * 3;
    const int* pj = pidx + (size_t)r * NCT * 3;
    for (int s = 0; s < NCT * 3; ++s) {
        float v = pv[s]; int j = pj[s];
        if (!(v > bv[NCAND - 1])) continue;
#pragma unroll
        for (int p = NCAND - 1; p > 0; --p) {
            bool hp = v > bv[p];
            bool gp = v > bv[p - 1];
            bv[p] = hp ? (gp ? bv[p - 1] : v) : bv[p];
            bj[p] = hp ? (gp ? bj[p - 1] : j) : bj[p];
        }
        bool h0 = v > bv[0];
        bv[0] = h0 ? v : bv[0];
        bj[0] = h0 ? j : bj[0];
    }

    const float* pr = proj + (size_t)r * DD;
    float myp[8];
#pragma unroll
    for (int k = 0; k < 8; ++k) myp[k] = pr[t * 8 + k];
    double part[NCAND];
#pragma unroll
    for (int i = 0; i < NCAND; ++i) {
        const float* pc = proj + (size_t)bj[i] * DD;
        double s = 0.0;
#pragma unroll
        for (int k = 0; k < 8; ++k) s += (double)myp[k] * (double)pc[t * 8 + k];
        part[i] = s;
    }
#pragma unroll
    for (int i = 0; i < NCAND; ++i) {
#pragma unroll
        for (int s = 1; s < 64; s <<= 1) part[i] += __shfl_xor(part[i], s, 64);
    }
    double bv0 = -1e300, bv1 = -1e300, bv2 = -1e300;
    int bj0 = 0x7fffffff, bj1 = 0x7fffffff, bj2 = 0x7fffffff;
#pragma unroll
    for (int i = 0; i < NCAND; ++i) {
        double v = part[i]; int j = bj[i];
        bool g2 = (v > bv2) || (v == bv2 && j < bj2);
        bool g1 = (v > bv1) || (v == bv1 && j < bj1);
        bool g0 = (v > bv0) || (v == bv0 && j < bj0);
        if (g2) {
            if (g1) {
                if (g0) { bv2 = bv1; bj2 = bj1; bv1 = bv0; bj1 = bj0; bv0 = v; bj0 = j; }
                else    { bv2 = bv1; bj2 = bj1; bv1 = v; bj1 = j; }
            } else      { bv2 = v; bj2 = j; }
        }
    }
    double e1 = exp(bv1 - bv0), e2 = exp(bv2 - bv0);
    double inv = 1.0 / (1.0 + e1 + e2);
    float w0 = (float)inv, w1 = (float)(e1 * inv), w2 = (float)(e2 * inv);
    if (t == 0) {
        cos_out[r * 3 + 0] = w0; cos_out[r * 3 + 1] = w1; cos_out[r * 3 + 2] = w2;
    }
    const float4* s0 = (const float4*)(sess + (size_t)bj0 * DD);
    const float4* s1 = (const float4*)(sess + (size_t)bj1 * DD);
    const float4* s2 = (const float4*)(sess + (size_t)bj2 * DD);
    float4* o = (float4*)(out + (size_t)r * 3 * DD);
    float4* nb = (float4*)(out + (size_t)NB * 3 * DD + (size_t)r * DD);
#pragma unroll
    for (int e = 0; e < 2; ++e) {
        int q = t + e * 64;          // float4 index 0..127
        float4 x0 = s0[q], x1 = s1[q], x2 = s2[q];
        o[q] = x0; o[128 + q] = x1; o[256 + q] = x2;
        float4 v;
        v.x = fmaf(w0, x0.x, fmaf(w1, x1.x, w2 * x2.x));
        v.y = fmaf(w0, x0.y, fmaf(w1, x1.y, w2 * x2.y));
        v.z = fmaf(w0, x0.z, fmaf(w1, x1.z, w2 * x2.z));
        v.w = fmaf(w0, x0.w, fmaf(w1, x1.w, w2 * x2.w));
        nb[q] = v;
    }
}

extern "C" void kernel_launch(void* const* d_in, const int* in_sizes, int n_in,
                              void* d_out, int out_size, void* d_ws, size_t ws_size,
                              hipStream_t stream) {
    const float* sess = (const float*)d_in[0];
    // d_in[1] = pool_emb: unused by the reference
    const float* W1 = (const float*)d_in[2];
    const float* b1 = (const float*)d_in[3];
    const float* W2 = (const float*)d_in[4];
    const float* b2 = (const float*)d_in[5];
    float* out = (float*)d_out;

    float* proj = (float*)d_ws;                                        // NB*DD f32
    __hip_bfloat16* projb = (__hip_bfloat16*)(proj + (size_t)NB * DD); // NB*DD bf16
    float* pvals = (float*)((char*)projb + (size_t)NB * DD * 2);       // NB*NCT*3 f32
    int*   pidx  = (int*)(pvals + (size_t)NB * NCT * 3);               // NB*NCT*3 i32

    float* cos_out = out + (size_t)NB * 3 * DD + (size_t)NB * DD;

    hipLaunchKernelGGL(mlp_kernel, dim3(NB / MR), dim3(256), 0, stream, sess, W1, b1, W2, b2, proj, projb);
    hipLaunchKernelGGL(sim_mfma_kernel, dim3(NB / BT, NB / BT), dim3(512), 131072, stream,
                       (const short*)projb, pvals, pidx);
    hipLaunchKernelGGL(rerank_out_kernel, dim3(NB), dim3(64), 0, stream, proj, pvals, pidx, sess, out, cos_out);
}

// Round 7
// 164.195 us; speedup vs baseline: 1.7885x; 1.7359x over previous
//
#include <hip/hip_runtime.h>
#include <hip/hip_bf16.h>
#include <math.h>

#define NB 8192
#define DD 512
#define HH 256
#define BM 128
#define BN 256
#define BK 32
#define KT (DD / BK)       // 16 k-tiles in sim
#define NCT (NB / BN)      // 32 column groups
#define NCAND 8

typedef unsigned short ushortT;
typedef __attribute__((ext_vector_type(8))) short bf16x8;
typedef __attribute__((ext_vector_type(4))) float f32x4;

#define AS1(p) ((const __attribute__((address_space(1))) void*)(p))
#define AS3(p) ((__attribute__((address_space(3))) void*)(p))

__device__ __forceinline__ ushortT bf16rne(float f) {
    unsigned u = __float_as_uint(f);
    unsigned r = u + 0x7FFFu + ((u >> 16) & 1u);
    return (ushortT)(r >> 16);
}
__device__ __forceinline__ float bf16tof(ushortT h) {
    return __uint_as_float(((unsigned)h) << 16);
}

// ---------------- Kernel 0: prep — split sess to bf16 hi/lo; transpose+split W1,W2 ----------------
__global__ __launch_bounds__(256)
void prep_kernel(const float* __restrict__ sess, const float* __restrict__ W1,
                 const float* __restrict__ W2,
                 ushortT* __restrict__ sess_hi, ushortT* __restrict__ sess_lo,
                 ushortT* __restrict__ w1t_hi, ushortT* __restrict__ w1t_lo,
                 ushortT* __restrict__ w2t_hi, ushortT* __restrict__ w2t_lo) {
    const int b = blockIdx.x, t = threadIdx.x;
    if (b < 2048) {
        // sess split: 8 consecutive floats per thread
        size_t i = (size_t)b * 2048 + t * 8;
        float4 f0 = *(const float4*)&sess[i];
        float4 f1 = *(const float4*)&sess[i + 4];
        float f[8] = {f0.x, f0.y, f0.z, f0.w, f1.x, f1.y, f1.z, f1.w};
        unsigned hp[4], lp[4];
#pragma unroll
        for (int j = 0; j < 4; ++j) {
            ushortT h0 = bf16rne(f[2 * j]), h1 = bf16rne(f[2 * j + 1]);
            ushortT l0 = bf16rne(f[2 * j] - bf16tof(h0));
            ushortT l1 = bf16rne(f[2 * j + 1] - bf16tof(h1));
            hp[j] = (unsigned)h0 | ((unsigned)h1 << 16);
            lp[j] = (unsigned)l0 | ((unsigned)l1 << 16);
        }
        *(uint4*)&sess_hi[i] = *(uint4*)hp;
        *(uint4*)&sess_lo[i] = *(uint4*)lp;
    } else if (b < 2112) {
        // W1 [512][256] -> W1T hi/lo [256][512]
        int o = (b - 2048) * 2048 + t * 8;
        int k = o >> 8, c = o & 255;
        float4 f0 = *(const float4*)&W1[(size_t)k * 256 + c];
        float4 f1 = *(const float4*)&W1[(size_t)k * 256 + c + 4];
        float f[8] = {f0.x, f0.y, f0.z, f0.w, f1.x, f1.y, f1.z, f1.w};
#pragma unroll
        for (int j = 0; j < 8; ++j) {
            ushortT h = bf16rne(f[j]);
            w1t_hi[(size_t)(c + j) * 512 + k] = h;
            w1t_lo[(size_t)(c + j) * 512 + k] = bf16rne(f[j] - bf16tof(h));
        }
    } else {
        // W2 [256][512] -> W2T hi/lo [512][256]
        int o = (b - 2112) * 2048 + t * 8;
        int k = o >> 9, c = o & 511;
        float4 f0 = *(const float4*)&W2[(size_t)k * 512 + c];
        float4 f1 = *(const float4*)&W2[(size_t)k * 512 + c + 4];
        float f[8] = {f0.x, f0.y, f0.z, f0.w, f1.x, f1.y, f1.z, f1.w};
#pragma unroll
        for (int j = 0; j < 8; ++j) {
            ushortT h = bf16rne(f[j]);
            w2t_hi[(size_t)(c + j) * 256 + k] = h;
            w2t_lo[(size_t)(c + j) * 256 + k] = bf16rne(f[j] - bf16tof(h));
        }
    }
}

// -------- Kernel 1/2: split-bf16 MFMA GEMM, C = A @ B^T (+bias), 64x256 tile --------
// A hi/lo [M][KDIM], B(T) hi/lo [NOUT][KDIM]. acc += Ah*Bh + Ah*Bl + Al*Bh.
// EPI 0: relu + split -> Ohi/Olo.  EPI 1: store f32 Of + bf16 Ob.
template <int KDIM, int NOUT, int EPI>
__global__ __launch_bounds__(256)
void mlp_gemm(const ushortT* __restrict__ Ahi, const ushortT* __restrict__ Alo,
              const ushortT* __restrict__ Bhi, const ushortT* __restrict__ Blo,
              const float* __restrict__ bias,
              ushortT* __restrict__ Ohi, ushortT* __restrict__ Olo,
              float* __restrict__ Of, ushortT* __restrict__ Ob) {
    __shared__ short gsmem[2 * 20480];   // 80 KB: per buf {Ahi 2K, Alo 2K, Bhi 8K, Blo 8K} shorts
    const int KTILES = KDIM / BK;
    const int t = threadIdx.x;
    const int w = t >> 6, l = t & 63;
    const int wr = w >> 1, wc = w & 1;
    const int tx = l & 15, tg = l >> 4;
    const int rb = blockIdx.x * 64;
    const int cb = blockIdx.y * 256;

    const int rin = l >> 2;
    const int tgs = (l & 3) ^ ((rin >> 1) & 3);
    const int loff = tx * BK + ((tg ^ ((tx >> 1) & 3)) << 3);

    f32x4 acc[2][8];
#pragma unroll
    for (int i = 0; i < 2; ++i)
#pragma unroll
        for (int j = 0; j < 8; ++j) acc[i][j] = (f32x4){0.f, 0.f, 0.f, 0.f};

#define GSTAGE(buf, k0v)                                                                     \
    {                                                                                        \
        _Pragma("unroll")                                                                    \
        for (int q = 0; q < 10; ++q) {                                                       \
            int c = w * 10 + q;                                                              \
            const ushortT* src; int row; int lofs;                                           \
            if (c < 4)       { src = Ahi; row = rb + c * 16 + rin;        lofs = 0     + c * 512; }        \
            else if (c < 8)  { src = Alo; row = rb + (c - 4) * 16 + rin;  lofs = 2048  + (c - 4) * 512; }  \
            else if (c < 24) { src = Bhi; row = cb + (c - 8) * 16 + rin;  lofs = 4096  + (c - 8) * 512; }  \
            else             { src = Blo; row = cb + (c - 24) * 16 + rin; lofs = 12288 + (c - 24) * 512; } \
            const ushortT* g = src + (size_t)row * KDIM + (k0v) + tgs * 8;                   \
            __builtin_amdgcn_global_load_lds(AS1(g), AS3(gsmem + (buf) * 20480 + lofs + l * 8), 16, 0, 0); \
        }                                                                                    \
    }

#define GCOMPUTE(kt)                                                                         \
    {                                                                                        \
        const short* Bu = gsmem + ((kt) & 1) * 20480;                                        \
        bf16x8 ah[2], al[2], bh[8], bl[8];                                                   \
        _Pragma("unroll")                                                                    \
        for (int mi = 0; mi < 2; ++mi) {                                                     \
            ah[mi] = *(const bf16x8*)&Bu[0 + (wr * 2 + mi) * 512 + loff];                    \
            al[mi] = *(const bf16x8*)&Bu[2048 + (wr * 2 + mi) * 512 + loff];                 \
        }                                                                                    \
        _Pragma("unroll")                                                                    \
        for (int nj = 0; nj < 8; ++nj) {                                                     \
            bh[nj] = *(const bf16x8*)&Bu[4096 + (wc * 8 + nj) * 512 + loff];                 \
            bl[nj] = *(const bf16x8*)&Bu[12288 + (wc * 8 + nj) * 512 + loff];                \
        }                                                                                    \
        asm volatile("s_waitcnt lgkmcnt(0)" ::: "memory");                                   \
        __builtin_amdgcn_sched_barrier(0);                                                   \
        __builtin_amdgcn_s_barrier();                                                        \
        __builtin_amdgcn_sched_barrier(0);                                                   \
        _Pragma("unroll")                                                                    \
        for (int mi = 0; mi < 2; ++mi)                                                       \
            _Pragma("unroll")                                                                \
            for (int nj = 0; nj < 8; ++nj) {                                                 \
                acc[mi][nj] = __builtin_amdgcn_mfma_f32_16x16x32_bf16(ah[mi], bh[nj], acc[mi][nj], 0, 0, 0); \
                acc[mi][nj] = __builtin_amdgcn_mfma_f32_16x16x32_bf16(ah[mi], bl[nj], acc[mi][nj], 0, 0, 0); \
                acc[mi][nj] = __builtin_amdgcn_mfma_f32_16x16x32_bf16(al[mi], bh[nj], acc[mi][nj], 0, 0, 0); \
            }                                                                                \
    }

    GSTAGE(0, 0);
    for (int kt = 0; kt < KTILES - 1; ++kt) {
        GSTAGE((kt + 1) & 1, (kt + 1) * BK);
        asm volatile("s_waitcnt vmcnt(10)" ::: "memory");
        __builtin_amdgcn_sched_barrier(0);
        __builtin_amdgcn_s_barrier();
        __builtin_amdgcn_sched_barrier(0);
        GCOMPUTE(kt);
    }
    asm volatile("s_waitcnt vmcnt(0)" ::: "memory");
    __builtin_amdgcn_sched_barrier(0);
    __builtin_amdgcn_s_barrier();
    __builtin_amdgcn_sched_barrier(0);
    GCOMPUTE(KTILES - 1);
#undef GSTAGE
#undef GCOMPUTE

    // epilogue
#pragma unroll
    for (int mi = 0; mi < 2; ++mi) {
#pragma unroll
        for (int nj = 0; nj < 8; ++nj) {
            int col = cb + wc * 128 + nj * 16 + tx;
            float bv = bias[col];
#pragma unroll
            for (int rr = 0; rr < 4; ++rr) {
                int row = rb + wr * 32 + mi * 16 + tg * 4 + rr;
                float v = acc[mi][nj][rr] + bv;
                if (EPI == 0) {
                    v = fmaxf(v, 0.f);
                    ushortT h = bf16rne(v);
                    Ohi[(size_t)row * NOUT + col] = h;
                    Olo[(size_t)row * NOUT + col] = bf16rne(v - bf16tof(h));
                } else {
                    Of[(size_t)row * NOUT + col] = v;
                    Ob[(size_t)row * NOUT + col] = bf16rne(v);
                }
            }
        }
    }
}

// ---- packed-key top-3 helpers (u32 key = monotone(f32)&~0x1FFF | (8191-col)) ----
__device__ __forceinline__ void ins3k(unsigned key, unsigned& k0, unsigned& k1, unsigned& k2) {
    bool g0 = key > k0, g1 = key > k1, g2 = key > k2;
    k2 = g1 ? k1 : (g2 ? key : k2);
    k1 = g0 ? k0 : (g1 ? key : k1);
    k0 = g0 ? key : k0;
}
__device__ __forceinline__ void merge3k(unsigned& a0, unsigned& a1, unsigned& a2,
                                        unsigned b0, unsigned b1, unsigned b2) {
    unsigned m0 = a0 > b0 ? a0 : b0;
    bool c0 = a0 > b0;
    unsigned ca1 = c0 ? a1 : b1;   // runner-up of winner side
    unsigned cb0 = c0 ? b0 : a0;   // top of loser side
    unsigned ca2 = c0 ? a2 : b2;
    unsigned cb1 = c0 ? b1 : a1;
    bool c1 = ca1 > cb0;
    unsigned m1 = c1 ? ca1 : cb0;
    unsigned x = c1 ? ca2 : ca1;
    unsigned y = c1 ? cb0 : cb1;
    unsigned m2 = x > y ? x : y;
    a0 = m0; a1 = m1; a2 = m2;
}

// ------------- Kernel 3: bf16 MFMA sim (128x256), R4 loop, packed-key top-3 epilogue -------------
__global__ __launch_bounds__(256)
void sim_mfma_kernel(const short* __restrict__ projb, unsigned* __restrict__ pkeys) {
    __shared__ short smem[2 * BM * BK + 2 * BN * BK];   // 48 KB
    short* As = smem;                 // [2][BM*BK]
    short* Bs = smem + 2 * BM * BK;   // [2][BN*BK]
    unsigned* evu = (unsigned*)smem;  // epilogue overlay [128][25] u32

    const int t = threadIdx.x;
    const int w = t >> 6, l = t & 63;
    const int wr = w >> 1, wc = w & 1;
    const int tx = l & 15, tg = l >> 4;
    const int rb = blockIdx.x * BM;
    const int jb = blockIdx.y * BN;

    const int rin = l >> 2;
    const int tgs = (l & 3) ^ ((rin >> 1) & 3);
    const int loff = tx * BK + ((tg ^ ((tx >> 1) & 3)) << 3);

    f32x4 acc[4][8];
#pragma unroll
    for (int i = 0; i < 4; ++i)
#pragma unroll
        for (int j = 0; j < 8; ++j) acc[i][j] = (f32x4){0.f, 0.f, 0.f, 0.f};

#define STAGE(buf, k0)                                                                      \
    {                                                                                       \
        _Pragma("unroll")                                                                   \
        for (int q = 0; q < 6; ++q) {                                                       \
            int c = w * 6 + q;                                                              \
            if (c < 8) {                                                                    \
                const short* g = projb + (size_t)(rb + c * 16 + rin) * DD + (k0) + tgs * 8; \
                __builtin_amdgcn_global_load_lds(AS1(g), AS3(As + (buf) * (BM * BK) + c * 512), 16, 0, 0); \
            } else {                                                                        \
                int cb = c - 8;                                                             \
                const short* g = projb + (size_t)(jb + cb * 16 + rin) * DD + (k0) + tgs * 8; \
                __builtin_amdgcn_global_load_lds(AS1(g), AS3(Bs + (buf) * (BN * BK) + cb * 512), 16, 0, 0); \
            }                                                                               \
        }                                                                                   \
    }

#define COMPUTE(kt)                                                                          \
    {                                                                                        \
        const short* Ab = As + ((kt) & 1) * (BM * BK);                                       \
        const short* Bb = Bs + ((kt) & 1) * (BN * BK);                                       \
        bf16x8 af[4], bfr[8];                                                                \
        _Pragma("unroll")                                                                    \
        for (int mi = 0; mi < 4; ++mi)                                                       \
            af[mi] = *(const bf16x8*)&Ab[(wr * 64 + mi * 16) * BK + loff];                   \
        _Pragma("unroll")                                                                    \
        for (int nj = 0; nj < 8; ++nj)                                                       \
            bfr[nj] = *(const bf16x8*)&Bb[(wc * 128 + nj * 16) * BK + loff];                 \
        asm volatile("s_waitcnt lgkmcnt(0)" ::: "memory");                                   \
        __builtin_amdgcn_sched_barrier(0);                                                   \
        __builtin_amdgcn_s_barrier();                                                        \
        __builtin_amdgcn_sched_barrier(0);                                                   \
        _Pragma("unroll")                                                                    \
        for (int mi = 0; mi < 4; ++mi)                                                       \
            _Pragma("unroll")                                                                \
            for (int nj = 0; nj < 8; ++nj)                                                   \
                acc[mi][nj] = __builtin_amdgcn_mfma_f32_16x16x32_bf16(af[mi], bfr[nj], acc[mi][nj], 0, 0, 0); \
    }

    STAGE(0, 0);
    for (int kt = 0; kt < KT - 1; ++kt) {
        STAGE((kt + 1) & 1, (kt + 1) * BK);
        asm volatile("s_waitcnt vmcnt(6)" ::: "memory");
        __builtin_amdgcn_sched_barrier(0);
        __builtin_amdgcn_s_barrier();
        __builtin_amdgcn_sched_barrier(0);
        COMPUTE(kt);
    }
    asm volatile("s_waitcnt vmcnt(0)" ::: "memory");
    __builtin_amdgcn_sched_barrier(0);
    __builtin_amdgcn_s_barrier();
    __builtin_amdgcn_sched_barrier(0);
    COMPUTE(KT - 1);
#undef STAGE
#undef COMPUTE

    __syncthreads();   // K-loop done everywhere before ev overlay

    // ---- epilogue: pack u32 keys, per-lane top3, 2-step butterfly, dump, per-row scan ----
    unsigned cinv[8];
#pragma unroll
    for (int nj = 0; nj < 8; ++nj)
        cinv[nj] = 8191u - (unsigned)(jb + wc * 128 + nj * 16 + tx);
#pragma unroll
    for (int mi = 0; mi < 4; ++mi) {
#pragma unroll
        for (int rr = 0; rr < 4; ++rr) {
            unsigned k0 = 0, k1 = 0, k2 = 0;
#pragma unroll
            for (int nj = 0; nj < 8; ++nj) {
                unsigned u = __float_as_uint(acc[mi][nj][rr]);
                unsigned tt = (unsigned)((int)u >> 31) | 0x80000000u;
                unsigned key = ((u ^ tt) & 0xFFFFE000u) | cinv[nj];
                ins3k(key, k0, k1, k2);
            }
#pragma unroll
            for (int s = 1; s <= 2; s <<= 1) {
                unsigned b0 = (unsigned)__shfl_xor((int)k0, s, 64);
                unsigned b1 = (unsigned)__shfl_xor((int)k1, s, 64);
                unsigned b2 = (unsigned)__shfl_xor((int)k2, s, 64);
                merge3k(k0, k1, k2, b0, b1, b2);
            }
            if ((tx & 3) == 0) {
                int lrow = wr * 64 + mi * 16 + tg * 4 + rr;
                unsigned* e = &evu[lrow * 25 + (wc * 4 + (tx >> 2)) * 3];
                e[0] = k0; e[1] = k1; e[2] = k2;
            }
        }
    }
    __syncthreads();
    if (t < BM) {
        unsigned k0 = 0, k1 = 0, k2 = 0;
        const unsigned* e = &evu[t * 25];
#pragma unroll
        for (int s = 0; s < 24; ++s) ins3k(e[s], k0, k1, k2);
        unsigned* pk = pkeys + ((size_t)(rb + t) * NCT + blockIdx.y) * 3;
        pk[0] = k0; pk[1] = k1; pk[2] = k2;
    }
}

// --- Kernel 4: merge 96 keys -> top-8, exact fp64 re-rank + softmax + gather + out ---
__global__ __launch_bounds__(64)
void rerank_out_kernel(const float* __restrict__ proj, const unsigned* __restrict__ pkeys,
                       const float* __restrict__ sess, float* __restrict__ out,
                       float* __restrict__ cos_out) {
    int r = blockIdx.x;
    int t = threadIdx.x;     // 64 lanes = 1 wave
    unsigned bk[NCAND];
#pragma unroll
    for (int p = 0; p < NCAND; ++p) bk[p] = 0;
    const unsigned* pk = pkeys + (size_t)r * NCT * 3;
    for (int s = 0; s < NCT * 3; ++s) {
        unsigned key = pk[s];
        if (key > bk[NCAND - 1]) {
#pragma unroll
            for (int p = NCAND - 1; p > 0; --p)
                bk[p] = (key > bk[p]) ? ((key > bk[p - 1]) ? bk[p - 1] : key) : bk[p];
            bk[0] = key > bk[0] ? key : bk[0];
        }
    }
    int cj[NCAND];
#pragma unroll
    for (int i = 0; i < NCAND; ++i) cj[i] = 8191 - (int)(bk[i] & 0x1FFFu);

    const float* pr = proj + (size_t)r * DD;
    float myp[8];
#pragma unroll
    for (int k = 0; k < 8; ++k) myp[k] = pr[t * 8 + k];
    double part[NCAND];
#pragma unroll
    for (int i = 0; i < NCAND; ++i) {
        const float* pc = proj + (size_t)cj[i] * DD;
        double s = 0.0;
#pragma unroll
        for (int k = 0; k < 8; ++k) s += (double)myp[k] * (double)pc[t * 8 + k];
        part[i] = s;
    }
#pragma unroll
    for (int i = 0; i < NCAND; ++i) {
#pragma unroll
        for (int s = 1; s < 64; s <<= 1) part[i] += __shfl_xor(part[i], s, 64);
    }
    double bv0 = -1e300, bv1 = -1e300, bv2 = -1e300;
    int bj0 = 0x7fffffff, bj1 = 0x7fffffff, bj2 = 0x7fffffff;
#pragma unroll
    for (int i = 0; i < NCAND; ++i) {
        double v = part[i]; int j = cj[i];
        bool g2 = (v > bv2) || (v == bv2 && j < bj2);
        bool g1 = (v > bv1) || (v == bv1 && j < bj1);
        bool g0 = (v > bv0) || (v == bv0 && j < bj0);
        if (g2) {
            if (g1) {
                if (g0) { bv2 = bv1; bj2 = bj1; bv1 = bv0; bj1 = bj0; bv0 = v; bj0 = j; }
                else    { bv2 = bv1; bj2 = bj1; bv1 = v; bj1 = j; }
            } else      { bv2 = v; bj2 = j; }
        }
    }
    double e1 = exp(bv1 - bv0), e2 = exp(bv2 - bv0);
    double inv = 1.0 / (1.0 + e1 + e2);
    float w0 = (float)inv, w1 = (float)(e1 * inv), w2 = (float)(e2 * inv);
    if (t == 0) {
        cos_out[r * 3 + 0] = w0; cos_out[r * 3 + 1] = w1; cos_out[r * 3 + 2] = w2;
    }
    const float4* s0 = (const float4*)(sess + (size_t)bj0 * DD);
    const float4* s1 = (const float4*)(sess + (size_t)bj1 * DD);
    const float4* s2 = (const float4*)(sess + (size_t)bj2 * DD);
    float4* o = (float4*)(out + (size_t)r * 3 * DD);
    float4* nb = (float4*)(out + (size_t)NB * 3 * DD + (size_t)r * DD);
#pragma unroll
    for (int e = 0; e < 2; ++e) {
        int q = t + e * 64;
        float4 x0 = s0[q], x1 = s1[q], x2 = s2[q];
        o[q] = x0; o[128 + q] = x1; o[256 + q] = x2;
        float4 v;
        v.x = fmaf(w0, x0.x, fmaf(w1, x1.x, w2 * x2.x));
        v.y = fmaf(w0, x0.y, fmaf(w1, x1.y, w2 * x2.y));
        v.z = fmaf(w0, x0.z, fmaf(w1, x1.z, w2 * x2.z));
        v.w = fmaf(w0, x0.w, fmaf(w1, x1.w, w2 * x2.w));
        nb[q] = v;
    }
}

extern "C" void kernel_launch(void* const* d_in, const int* in_sizes, int n_in,
                              void* d_out, int out_size, void* d_ws, size_t ws_size,
                              hipStream_t stream) {
    const float* sess = (const float*)d_in[0];
    // d_in[1] = pool_emb: unused by the reference
    const float* W1 = (const float*)d_in[2];
    const float* b1 = (const float*)d_in[3];
    const float* W2 = (const float*)d_in[4];
    const float* b2 = (const float*)d_in[5];
    float* out = (float*)d_out;

    const size_t MBc = 1u << 20;
    char* W = (char*)d_ws;
    // [0,16MB): sess_hi+sess_lo during prep/gemm1; proj f32 afterwards (stream-serialized)
    float*   proj    = (float*)W;
    ushortT* sess_hi = (ushortT*)W;                       // 8 MB
    ushortT* sess_lo = sess_hi + (size_t)NB * DD;         // 8 MB
    ushortT* projb   = (ushortT*)(W + 16 * MBc);          // 8 MB
    ushortT* h_hi    = (ushortT*)(W + 24 * MBc);          // 4 MB
    ushortT* h_lo    = (ushortT*)(W + 28 * MBc);          // 4 MB
    ushortT* w1t_hi  = (ushortT*)(W + 32 * MBc);          // 256 KB
    ushortT* w1t_lo  = w1t_hi + 256 * 512;
    ushortT* w2t_hi  = w1t_lo + 256 * 512;
    ushortT* w2t_lo  = w2t_hi + 512 * 256;
    unsigned* pkeys  = (unsigned*)(W + 33 * MBc);         // 3 MB

    float* cos_out = out + (size_t)NB * 3 * DD + (size_t)NB * DD;

    hipLaunchKernelGGL(prep_kernel, dim3(2176), dim3(256), 0, stream,
                       sess, W1, W2, sess_hi, sess_lo, w1t_hi, w1t_lo, w2t_hi, w2t_lo);
    hipLaunchKernelGGL((mlp_gemm<512, 256, 0>), dim3(NB / 64, 1), dim3(256), 0, stream,
                       sess_hi, sess_lo, w1t_hi, w1t_lo, b1, h_hi, h_lo, (float*)nullptr, (ushortT*)nullptr);
    hipLaunchKernelGGL((mlp_gemm<256, 512, 1>), dim3(NB / 64, 2), dim3(256), 0, stream,
                       h_hi, h_lo, w2t_hi, w2t_lo, b2, (ushortT*)nullptr, (ushortT*)nullptr, proj, projb);
    hipLaunchKernelGGL(sim_mfma_kernel, dim3(NB / BM, NCT), dim3(256), 0, stream,
                       (const short*)projb, pkeys);
    hipLaunchKernelGGL(rerank_out_kernel, dim3(NB), dim3(64), 0, stream,
                       proj, pkeys, sess, out, cos_out);
}